// Round 2
// baseline (774.496 us; speedup 1.0000x reference)
//
#include <hip/hip_runtime.h>

// TopK-and-scatter: out[r,c] = x[r,c] if x[r,c] is among the top-64 of row r
// (ties at threshold broken by LOWEST column index, matching lax.top_k), else 0.
// Exact radix select on order-preserving uint32 keys; row resident in registers.
// R2: hierarchical shuffle-based suffix scans (3 barriers/round instead of ~20),
// histogram re-zeroing folded into existing barrier windows, nontemporal
// loads/stores, VGPR capped for 2 blocks/CU (32 waves).

typedef float f32x4 __attribute__((ext_vector_type(4)));
typedef unsigned int u32;
typedef u32 u32x4 __attribute__((ext_vector_type(4)));

#define TPB   1024
#define COLS  32768
#define EPT   32
#define KSEL  64u

__global__ __launch_bounds__(TPB, 8) void topk_scatter_kernel(
    const float* __restrict__ x, float* __restrict__ out)
{
    __shared__ u32 hist[4096];
    __shared__ u32 wtot[16];
    __shared__ u32 wsuf[16];
    __shared__ int sBin;
    __shared__ u32 sAbove;
    __shared__ u32 sEqCnt;
    __shared__ u32 eqN;
    __shared__ int eqIdx[256];

    const int tid  = threadIdx.x;
    const int lane = tid & 63;
    const int wid  = tid >> 6;

    const long long row = blockIdx.x;
    const f32x4* __restrict__ xrow = (const f32x4*)(x + row * (long long)COLS);
    f32x4* __restrict__ orow       = (f32x4*)(out + row * (long long)COLS);

    // zero round-1 histogram (4096 bins, 4 per thread, one b128 store)
    ((u32x4*)hist)[tid] = (u32x4)(0u);

    // ---- load row into registers as order-preserving keys ----
    u32 key[EPT];
    #pragma unroll
    for (int j = 0; j < 8; ++j) {
        const f32x4 v = __builtin_nontemporal_load(&xrow[j * TPB + tid]);
        #pragma unroll
        for (int l = 0; l < 4; ++l) {
            const u32 b = __float_as_uint(v[l]);
            key[j * 4 + l] = b ^ ((u32)((int)b >> 31) | 0x80000000u);
        }
    }
    __syncthreads();

    // ---- Round 1: histogram bits [31:20], 4096 bins ----
    #pragma unroll
    for (int e = 0; e < EPT; ++e) atomicAdd(&hist[key[e] >> 20], 1u);
    __syncthreads();

    u32 need = KSEL;

    // ---- Round 1 scan: thread owns bins [4*tid, 4*tid+4) ----
    {
        const u32x4 h = ((const u32x4*)hist)[tid];   // ds_read_b128, own bins
        const u32 ls3 = h[3];
        const u32 ls2 = h[2] + ls3;
        const u32 ls1 = h[1] + ls2;
        const u32 ls0 = h[0] + ls1;
        u32 v = ls0;                                  // wave suffix scan (no LDS)
        #pragma unroll
        for (int off = 1; off < 64; off <<= 1) {
            const u32 t = __shfl_down(v, off);
            if (lane + off < 64) v += t;
        }
        if (lane == 0) wtot[wid] = v;
        __syncthreads();
        if (wid == 0) {
            u32 s = (lane < 16) ? wtot[lane] : 0u;
            #pragma unroll
            for (int off = 1; off < 16; off <<= 1) {
                const u32 t = __shfl_down(s, off);
                if (lane + off < 64) s += t;
            }
            if (lane < 16) wsuf[lane] = s;
        }
        // zero bins 0..1023 for round 2 (reads of hist are done; barrier below
        // orders this before round-2 atomics)
        hist[tid] = 0u;
        __syncthreads();
        const u32 tailWaves = (wid < 15) ? wsuf[wid + 1] : 0u;
        const u32 thrTail   = tailWaves + (v - ls0);  // suffix of bin 4*tid+4
        const u32 S0 = ls0 + thrTail, S1 = ls1 + thrTail, S2 = ls2 + thrTail,
                  S3 = ls3 + thrTail, S4 = thrTail;
        if (S0 >= need && S1 < need) { sBin = 4 * tid + 0; sAbove = S1; }
        if (S1 >= need && S2 < need) { sBin = 4 * tid + 1; sAbove = S2; }
        if (S2 >= need && S3 < need) { sBin = 4 * tid + 2; sAbove = S3; }
        if (S3 >= need && S4 < need) { sBin = 4 * tid + 3; sAbove = S4; }
        __syncthreads();
    }
    const u32 b1 = (u32)sBin;
    need -= sAbove;

    // ---- Round 2: bits [19:10] among prefix-matching, 1024 bins ----
    #pragma unroll
    for (int e = 0; e < EPT; ++e)
        if ((key[e] >> 20) == b1) atomicAdd(&hist[(key[e] >> 10) & 1023u], 1u);
    __syncthreads();
    {
        const u32 hh = hist[tid];
        hist[tid] = 0u;                               // own bin; zero for round 3
        u32 v = hh;
        #pragma unroll
        for (int off = 1; off < 64; off <<= 1) {
            const u32 t = __shfl_down(v, off);
            if (lane + off < 64) v += t;
        }
        if (lane == 0) wtot[wid] = v;
        __syncthreads();
        if (wid == 0) {
            u32 s = (lane < 16) ? wtot[lane] : 0u;
            #pragma unroll
            for (int off = 1; off < 16; off <<= 1) {
                const u32 t = __shfl_down(s, off);
                if (lane + off < 64) s += t;
            }
            if (lane < 16) wsuf[lane] = s;
        }
        __syncthreads();
        const u32 tailWaves = (wid < 15) ? wsuf[wid + 1] : 0u;
        const u32 thrTail   = tailWaves + (v - hh);
        const u32 S0 = hh + thrTail, S1 = thrTail;
        if (S0 >= need && S1 < need) { sBin = tid; sAbove = S1; }
        __syncthreads();
    }
    const u32 pfx2 = (b1 << 10) | (u32)sBin;
    need -= sAbove;

    // ---- Round 3: bits [9:0] among prefix-matching, 1024 bins ----
    #pragma unroll
    for (int e = 0; e < EPT; ++e)
        if ((key[e] >> 10) == pfx2) atomicAdd(&hist[key[e] & 1023u], 1u);
    __syncthreads();
    {
        const u32 hh = hist[tid];
        u32 v = hh;
        #pragma unroll
        for (int off = 1; off < 64; off <<= 1) {
            const u32 t = __shfl_down(v, off);
            if (lane + off < 64) v += t;
        }
        if (lane == 0) wtot[wid] = v;
        __syncthreads();
        if (wid == 0) {
            u32 s = (lane < 16) ? wtot[lane] : 0u;
            #pragma unroll
            for (int off = 1; off < 16; off <<= 1) {
                const u32 t = __shfl_down(s, off);
                if (lane + off < 64) s += t;
            }
            if (lane < 16) wsuf[lane] = s;
        }
        __syncthreads();
        const u32 tailWaves = (wid < 15) ? wsuf[wid + 1] : 0u;
        const u32 thrTail   = tailWaves + (v - hh);
        const u32 S0 = hh + thrTail, S1 = thrTail;
        if (S0 >= need && S1 < need) { sBin = tid; sAbove = S1; sEqCnt = hh; }
        __syncthreads();
    }
    const u32 b3     = (u32)sBin;
    const u32 above3 = sAbove;
    const u32 T      = (pfx2 << 10) | b3;   // exact k-th key
    const u32 eqCnt  = sEqCnt;              // # keys == T
    const u32 needEq = need - above3;       // how many equals to keep

    // ---- exact tie handling: keep the needEq SMALLEST column indices ----
    const bool tieAll = (needEq == eqCnt);
    if (tid == 0) eqN = 0u;
    __syncthreads();
    if (!tieAll) {
        #pragma unroll
        for (int e = 0; e < EPT; ++e) {
            if (key[e] == T) {
                const u32 p = atomicAdd(&eqN, 1u);
                if (p < 256u) eqIdx[p] = ((e >> 2) * TPB + tid) * 4 + (e & 3);
            }
        }
    }
    __syncthreads();
    const u32 eqM = (eqN < 256u) ? eqN : 256u;

    // ---- write pass: selected values (bit-exact), zeros elsewhere ----
    #pragma unroll
    for (int j = 0; j < 8; ++j) {
        f32x4 o;
        #pragma unroll
        for (int l = 0; l < 4; ++l) {
            const u32 k = key[j * 4 + l];
            bool sel;
            if (k != T) {
                sel = (k > T);
            } else if (tieAll) {
                sel = true;
            } else {
                const int col = (j * TPB + tid) * 4 + l;
                u32 r = 0;
                for (u32 q = 0; q < eqM; ++q)
                    r += (eqIdx[q] < col) ? 1u : 0u;
                sel = (r < needEq);
            }
            const float val =
                __uint_as_float((k & 0x80000000u) ? (k ^ 0x80000000u) : ~k);
            o[l] = sel ? val : 0.0f;
        }
        __builtin_nontemporal_store(o, &orow[j * TPB + tid]);
    }
}

extern "C" void kernel_launch(void* const* d_in, const int* in_sizes, int n_in,
                              void* d_out, int out_size, void* d_ws, size_t ws_size,
                              hipStream_t stream)
{
    (void)n_in; (void)out_size; (void)d_ws; (void)ws_size;
    const float* x = (const float*)d_in[0];
    float* out = (float*)d_out;
    const int rows = in_sizes[0] / COLS;
    topk_scatter_kernel<<<dim3(rows), dim3(TPB), 0, stream>>>(x, out);
}

// Round 3
// 460.002 us; speedup vs baseline: 1.6837x; 1.6837x over previous
//
#include <hip/hip_runtime.h>

// TopK-and-scatter: out[r,c] = x[r,c] if x[r,c] is among the top-64 of row r
// (ties at threshold broken by LOWEST column index, matching lax.top_k), else 0.
// Exact radix select on order-preserving uint32 keys; row resident in registers.
// R3: R1's register regime (no waves-per-eu cap -> no spills, 2 blocks/CU) +
// shuffle-based hierarchical suffix scans (11 barriers/block vs R1's ~64).
// Plain loads/stores (R2's nt experiment confounded with spills; reverted).

typedef float f32x4 __attribute__((ext_vector_type(4)));
typedef unsigned int u32;
typedef u32 u32x4 __attribute__((ext_vector_type(4)));

#define TPB   1024
#define COLS  32768
#define EPT   32
#define KSEL  64u

__global__ __launch_bounds__(TPB) void topk_scatter_kernel(
    const float* __restrict__ x, float* __restrict__ out)
{
    __shared__ u32 hist[4096];
    __shared__ u32 wtot[16];
    __shared__ int sBin;
    __shared__ u32 sAbove;
    __shared__ u32 sEqCnt;
    __shared__ u32 eqN;
    __shared__ int eqIdx[256];

    const int tid  = threadIdx.x;
    const int lane = tid & 63;
    const int wid  = tid >> 6;

    const long long row = blockIdx.x;
    const f32x4* __restrict__ xrow = (const f32x4*)(x + row * (long long)COLS);
    f32x4* __restrict__ orow       = (f32x4*)(out + row * (long long)COLS);

    // zero round-1 histogram (4096 bins, 4 per thread, one b128 store)
    ((u32x4*)hist)[tid] = (u32x4)(0u);

    // ---- load row into registers as order-preserving keys ----
    u32 key[EPT];
    #pragma unroll
    for (int j = 0; j < 8; ++j) {
        const f32x4 v = xrow[j * TPB + tid];
        #pragma unroll
        for (int l = 0; l < 4; ++l) {
            const u32 b = __float_as_uint(v[l]);
            key[j * 4 + l] = b ^ ((u32)((int)b >> 31) | 0x80000000u);
        }
    }
    __syncthreads();                                   // A: hist zeroed

    // ---- Round 1: histogram bits [31:20], 4096 bins ----
    #pragma unroll
    for (int e = 0; e < EPT; ++e) atomicAdd(&hist[key[e] >> 20], 1u);
    __syncthreads();                                   // B: hist complete

    u32 need = KSEL;

    // ---- Round 1 scan: thread owns bins [4*tid, 4*tid+4) ----
    {
        const u32x4 h = ((const u32x4*)hist)[tid];     // own bins only
        const u32 ls3 = h[3];
        const u32 ls2 = h[2] + ls3;
        const u32 ls1 = h[1] + ls2;
        const u32 ls0 = h[0] + ls1;
        u32 v = ls0;                                   // wave suffix scan (shfl)
        #pragma unroll
        for (int off = 1; off < 64; off <<= 1) {
            const u32 t = __shfl_down(v, off);
            if (lane + off < 64) v += t;
        }
        if (lane == 0) wtot[wid] = v;                  // wave totals
        __syncthreads();                               // C: wtot ready
        u32 tailWaves = 0u;
        for (int w = wid + 1; w < 16; ++w) tailWaves += wtot[w];  // broadcast reads
        const u32 thrTail = tailWaves + (v - ls0);     // suffix past own 4 bins
        const u32 S0 = ls0 + thrTail, S1 = ls1 + thrTail, S2 = ls2 + thrTail,
                  S3 = ls3 + thrTail, S4 = thrTail;
        if (S0 >= need && S1 < need) { sBin = 4 * tid + 0; sAbove = S1; }
        if (S1 >= need && S2 < need) { sBin = 4 * tid + 1; sAbove = S2; }
        if (S2 >= need && S3 < need) { sBin = 4 * tid + 2; sAbove = S3; }
        if (S3 >= need && S4 < need) { sBin = 4 * tid + 3; sAbove = S4; }
        hist[tid] = 0u;                                // zero bins 0..1023 for r2
        __syncthreads();                               // D: sBin + zeros visible
    }
    const u32 b1 = (u32)sBin;
    need -= sAbove;

    // ---- Round 2: bits [19:10] among prefix-matching, 1024 bins ----
    #pragma unroll
    for (int e = 0; e < EPT; ++e)
        if ((key[e] >> 20) == b1) atomicAdd(&hist[(key[e] >> 10) & 1023u], 1u);
    __syncthreads();                                   // E: hist complete
    {
        const u32 hh = hist[tid];
        hist[tid] = 0u;                                // own bin; zero for r3
        u32 v = hh;
        #pragma unroll
        for (int off = 1; off < 64; off <<= 1) {
            const u32 t = __shfl_down(v, off);
            if (lane + off < 64) v += t;
        }
        if (lane == 0) wtot[wid] = v;
        __syncthreads();                               // F: wtot ready
        u32 tailWaves = 0u;
        for (int w = wid + 1; w < 16; ++w) tailWaves += wtot[w];
        const u32 thrTail = tailWaves + (v - hh);
        const u32 S0 = hh + thrTail, S1 = thrTail;
        if (S0 >= need && S1 < need) { sBin = tid; sAbove = S1; }
        __syncthreads();                               // G: sBin + zeros visible
    }
    const u32 pfx2 = (b1 << 10) | (u32)sBin;
    need -= sAbove;

    // ---- Round 3: bits [9:0] among prefix-matching, 1024 bins ----
    #pragma unroll
    for (int e = 0; e < EPT; ++e)
        if ((key[e] >> 10) == pfx2) atomicAdd(&hist[key[e] & 1023u], 1u);
    __syncthreads();                                   // H: hist complete
    {
        const u32 hh = hist[tid];
        u32 v = hh;
        #pragma unroll
        for (int off = 1; off < 64; off <<= 1) {
            const u32 t = __shfl_down(v, off);
            if (lane + off < 64) v += t;
        }
        if (lane == 0) wtot[wid] = v;
        if (tid == 0) eqN = 0u;
        __syncthreads();                               // I: wtot + eqN ready
        u32 tailWaves = 0u;
        for (int w = wid + 1; w < 16; ++w) tailWaves += wtot[w];
        const u32 thrTail = tailWaves + (v - hh);
        const u32 S0 = hh + thrTail, S1 = thrTail;
        if (S0 >= need && S1 < need) { sBin = tid; sAbove = S1; sEqCnt = hh; }
        __syncthreads();                               // J: threshold known
    }
    const u32 b3     = (u32)sBin;
    const u32 above3 = sAbove;
    const u32 T      = (pfx2 << 10) | b3;   // exact k-th key
    const u32 eqCnt  = sEqCnt;              // # keys == T
    const u32 needEq = need - above3;       // how many equals to keep

    // ---- exact tie handling: keep the needEq SMALLEST column indices ----
    const bool tieAll = (needEq == eqCnt);
    if (!tieAll) {
        #pragma unroll
        for (int e = 0; e < EPT; ++e) {
            if (key[e] == T) {
                const u32 p = atomicAdd(&eqN, 1u);
                if (p < 256u) eqIdx[p] = ((e >> 2) * TPB + tid) * 4 + (e & 3);
            }
        }
    }
    __syncthreads();                                   // K: tie list ready
    const u32 eqM = (eqN < 256u) ? eqN : 256u;

    // ---- write pass: selected values (bit-exact), zeros elsewhere ----
    #pragma unroll
    for (int j = 0; j < 8; ++j) {
        f32x4 o;
        #pragma unroll
        for (int l = 0; l < 4; ++l) {
            const u32 k = key[j * 4 + l];
            bool sel;
            if (k != T) {
                sel = (k > T);
            } else if (tieAll) {
                sel = true;
            } else {
                const int col = (j * TPB + tid) * 4 + l;
                u32 r = 0;
                for (u32 q = 0; q < eqM; ++q)
                    r += (eqIdx[q] < col) ? 1u : 0u;
                sel = (r < needEq);
            }
            const float val =
                __uint_as_float((k & 0x80000000u) ? (k ^ 0x80000000u) : ~k);
            o[l] = sel ? val : 0.0f;
        }
        orow[j * TPB + tid] = o;
    }
}

extern "C" void kernel_launch(void* const* d_in, const int* in_sizes, int n_in,
                              void* d_out, int out_size, void* d_ws, size_t ws_size,
                              hipStream_t stream)
{
    (void)n_in; (void)out_size; (void)d_ws; (void)ws_size;
    const float* x = (const float*)d_in[0];
    float* out = (float*)d_out;
    const int rows = in_sizes[0] / COLS;
    topk_scatter_kernel<<<dim3(rows), dim3(TPB), 0, stream>>>(x, out);
}